// Round 7
// baseline (546.767 us; speedup 1.0000x reference)
//
#include <hip/hip_runtime.h>
#include <hip/hip_bf16.h>

#define B_  64
#define T_  30
#define E_  300
#define H_  512
#define FD_ 512
#define V_  10000
#define NR_ 32          // recurrence WGs
#define NPW_ 224        // projection WGs
#define NTN_ 79         // N tiles of 128 covering V=10000
#define AGGF_ 1056      // aggregated epoch flag index in bar[] -- byte 4224, OWN cache
                        // line, disjoint from the 32 per-WG flag lines (bytes 0..4095)

typedef __attribute__((ext_vector_type(8))) unsigned short ushort8_t;
typedef __attribute__((ext_vector_type(4))) unsigned short ushort4_t;
typedef __attribute__((ext_vector_type(8))) __bf16 bf16x8;
typedef __attribute__((ext_vector_type(4))) float f32x4;

__device__ __forceinline__ float b2f(unsigned short u) {
    union { unsigned int i; float f; } v;
    v.i = ((unsigned int)u) << 16;
    return v.f;
}
__device__ __forceinline__ unsigned short f2b(float f) {
    unsigned int x = __builtin_bit_cast(unsigned int, f);
    unsigned int r = x + 0x7FFFu + ((x >> 16) & 1u);
    return (unsigned short)(r >> 16);
}
__device__ __forceinline__ f32x4 mfma16(bf16x8 a, bf16x8 b, f32x4 c) {
    return __builtin_amdgcn_mfma_f32_16x16x32_bf16(a, b, c, 0, 0, 0);
}

// ================= prep: all transposes + build_x + h0 conv + flag zero =================
struct PrepA {
    const float* tsrc[17];
    unsigned short* tdst[17];
    const int* captions;
    const float* features;
    const float* Bemb;
    unsigned short* X;          // stride 304
    const float* h0;
    unsigned short* cH0;
    int* bar;
};

__global__ __launch_bounds__(256) void prep_k(PrepA p) {
    const int blk = blockIdx.x, tid = threadIdx.x;
    __shared__ unsigned short tile[32][33];
    if (blk < 8720) {
        int z, bx, by, R, C, Rpad, ld;
        if (blk < 3072) { z = blk >> 8; int wq = blk & 255; bx = wq & 15; by = wq >> 4; R = 512; C = 512; Rpad = 512; ld = 512; }
        else if (blk < 3712) { int b2 = blk - 3072; z = 12 + b2 / 160; int wq = b2 % 160; bx = wq & 15; by = wq >> 4; R = 300; C = 512; Rpad = 320; ld = 320; }
        else { int b2 = blk - 3712; z = 16; bx = b2 % 313; by = b2 / 313; R = 512; C = 10000; Rpad = 512; ld = 512; }
        const float* __restrict__ src = p.tsrc[z];
        unsigned short* __restrict__ dst = p.tdst[z];
        const int tc = tid & 31, tr = tid >> 5;
        const int c0 = bx * 32, r0 = by * 32;
#pragma unroll
        for (int i = 0; i < 4; ++i) {
            int r = r0 + tr + i * 8, c = c0 + tc;
            unsigned short v = 0;
            if (r < R && c < C) v = f2b(src[(size_t)r * C + c]);
            tile[tr + i * 8][tc] = v;
        }
        __syncthreads();
#pragma unroll
        for (int i = 0; i < 4; ++i) {
            int c = c0 + tr + i * 8;
            int r = r0 + tc;
            if (c < C && r < Rpad) dst[(size_t)c * ld + r] = tile[tc][tr + i * 8];
        }
    } else if (blk < 11000) {
        int idx = (blk - 8720) * 256 + tid;          // over B*T*304
        if (idx < B_ * T_ * 304) {
            int r = idx / 304, e = idx - r * 304;
            int t = r >> 6, b = r & 63;
            float v = 0.f;
            if (e < E_) {
                if (t == 0) v = p.features[b * E_ + e];
                else {
                    int tok = p.captions[b * T_ + (t - 1)];
                    v = p.Bemb[(size_t)tok * E_ + e];
                }
            }
            p.X[(size_t)r * 304 + e] = f2b(v);
        }
    } else {
        int i = (blk - 11000) * 256 + tid;           // 128 blocks -> 32768 threads
        if (i < 2048) p.bar[i] = 0;                  // covers per-WG flags + AGGF_ line
        if (i < B_ * H_) p.cH0[i] = f2b(p.h0[i]);
    }
}

// ================= chain: fused 3-stage gate preactivation =================
struct ChainA {
    const unsigned short* X;      // [1920][304]
    const unsigned short* Vt[4];  // [512][320] (zero-padded K)
    const float* Vb[4];
    const unsigned short* St[4];  // [512][512]
    const float* Sb[4];
    const unsigned short* Ut[4];  // [512][512]
    const float* Ub[4];
    unsigned short* U[4];         // out [1920][512] bf16
};

__global__ __launch_bounds__(256) void chain_k(ChainA ca) {
    const int rb = blockIdx.x >> 2, g = blockIdx.x & 3;
    __shared__ char pool[133120];
    unsigned short* XT = (unsigned short*)pool;             // stage A in, stride 328
    unsigned short* R0 = (unsigned short*)pool;             // stage B out, stride 520
    unsigned short* R1 = (unsigned short*)(pool + 66560);   // stage A out, stride 520
    const int tid = threadIdx.x;
    const int wv = tid >> 6, lane = tid & 63;
    const int quad = lane >> 4, l16 = lane & 15;

    {
        const unsigned short* src = ca.X + (size_t)rb * 64 * 304;
#pragma unroll
        for (int it = 0; it < 10; ++it) {
            int id = it * 256 + tid;                        // 2560 chunks of 8
            int row = id / 40, c8 = (id % 40) * 8;
            ushort8_t v = {0, 0, 0, 0, 0, 0, 0, 0};
            if (c8 < 304) v = *(const ushort8_t*)(src + row * 304 + c8);
            *(ushort8_t*)&XT[row * 328 + c8] = v;
        }
    }
    __syncthreads();
    // ---- stage A: R1 = X @ Vt^T + Vb  (K=320 padded)
#pragma unroll
    for (int half = 0; half < 2; ++half) {
        const int cb = wv * 128 + half * 64;
        f32x4 acc[4][4] = {};
        for (int kc = 0; kc < 10; ++kc) {
            bf16x8 af[4];
#pragma unroll
            for (int mt = 0; mt < 4; ++mt)
                af[mt] = *(const bf16x8*)&XT[(mt * 16 + l16) * 328 + kc * 32 + quad * 8];
#pragma unroll
            for (int nt = 0; nt < 4; ++nt) {
                bf16x8 bf = *(const bf16x8*)(ca.Vt[g] + (size_t)(cb + nt * 16 + l16) * 320 + kc * 32 + quad * 8);
#pragma unroll
                for (int mt = 0; mt < 4; ++mt) acc[mt][nt] = mfma16(af[mt], bf, acc[mt][nt]);
            }
        }
#pragma unroll
        for (int mt = 0; mt < 4; ++mt)
#pragma unroll
            for (int nt = 0; nt < 4; ++nt) {
                int col = cb + nt * 16 + l16;
                float bv = ca.Vb[g][col];
#pragma unroll
                for (int r = 0; r < 4; ++r)
                    R1[(mt * 16 + quad * 4 + r) * 520 + col] = f2b(acc[mt][nt][r] + bv);
            }
    }
    __syncthreads();
    // ---- stage B: R0 = R1 @ St^T + Sb  (K=512)
#pragma unroll
    for (int half = 0; half < 2; ++half) {
        const int cb = wv * 128 + half * 64;
        f32x4 acc[4][4] = {};
        for (int kc = 0; kc < 16; ++kc) {
            bf16x8 af[4];
#pragma unroll
            for (int mt = 0; mt < 4; ++mt)
                af[mt] = *(const bf16x8*)&R1[(mt * 16 + l16) * 520 + kc * 32 + quad * 8];
#pragma unroll
            for (int nt = 0; nt < 4; ++nt) {
                bf16x8 bf = *(const bf16x8*)(ca.St[g] + (size_t)(cb + nt * 16 + l16) * 512 + kc * 32 + quad * 8);
#pragma unroll
                for (int mt = 0; mt < 4; ++mt) acc[mt][nt] = mfma16(af[mt], bf, acc[mt][nt]);
            }
        }
        __syncthreads();   // R0 aliases XT region; ensure pool reads done before overwrite
#pragma unroll
        for (int mt = 0; mt < 4; ++mt)
#pragma unroll
            for (int nt = 0; nt < 4; ++nt) {
                int col = cb + nt * 16 + l16;
                float bv = ca.Sb[g][col];
#pragma unroll
                for (int r = 0; r < 4; ++r)
                    R0[(mt * 16 + quad * 4 + r) * 520 + col] = f2b(acc[mt][nt][r] + bv);
            }
    }
    __syncthreads();
    // ---- stage C: global U = R0 @ Ut^T + Ub
#pragma unroll
    for (int half = 0; half < 2; ++half) {
        const int cb = wv * 128 + half * 64;
        f32x4 acc[4][4] = {};
        for (int kc = 0; kc < 16; ++kc) {
            bf16x8 af[4];
#pragma unroll
            for (int mt = 0; mt < 4; ++mt)
                af[mt] = *(const bf16x8*)&R0[(mt * 16 + l16) * 520 + kc * 32 + quad * 8];
#pragma unroll
            for (int nt = 0; nt < 4; ++nt) {
                bf16x8 bf = *(const bf16x8*)(ca.Ut[g] + (size_t)(cb + nt * 16 + l16) * 512 + kc * 32 + quad * 8);
#pragma unroll
                for (int mt = 0; mt < 4; ++mt) acc[mt][nt] = mfma16(af[mt], bf, acc[mt][nt]);
            }
        }
#pragma unroll
        for (int mt = 0; mt < 4; ++mt)
#pragma unroll
            for (int nt = 0; nt < 4; ++nt) {
                int col = cb + nt * 16 + l16;
                float bv = ca.Ub[g][col];
#pragma unroll
                for (int r = 0; r < 4; ++r)
                    ca.U[g][(size_t)(rb * 64 + mt * 16 + quad * 4 + r) * 512 + col] =
                        f2b(acc[mt][nt][r] + bv);
            }
    }
}

// ================= mega: recurrence (32 WGs) + flag-gated projection (224 WGs) =================
struct MegaA {
    const unsigned short* h0c;    // [B][H] bf16
    const unsigned short* Wt[4];  // [512][512]
    const float* Wb[4];
    const unsigned short* U[4];   // [1920][512] bf16
    const float* c0;              // f32
    unsigned short* Hall;         // [1920][512] bf16
    int* bar;                     // 32 flags at 128B stride + isolated aggregated flag
    const unsigned short* Ct;     // [10000][512] bf16
    const float* Cb;
    float* out;                   // [B][T][V] f32
};

__global__ __launch_bounds__(256, 1) void mega_k(MegaA a) {
    __shared__ char pool[83712];
    const int tid = threadIdx.x;
    const int lane = tid & 63;
    const int quad = lane >> 4, l16 = lane & 15;

    if (blockIdx.x < NR_) {
        // -------- recurrence WG: owns h-cols [j*16, j*16+16), wave g = gate
        unsigned short* hs = (unsigned short*)pool;       // 64 x 520
        float* xch = (float*)(pool + 66560);              // [4][16*65]
        const int j = blockIdx.x;
        const int g = tid >> 6;
        bf16x8 afrag[16];
        {
            const unsigned short* wt = a.Wt[g] + (size_t)(j * 16 + l16) * H_ + quad * 8;
#pragma unroll
            for (int kc = 0; kc < 16; ++kc) afrag[kc] = *(const bf16x8*)(wt + kc * 32);
        }
        const int eb = tid >> 2;
        const int ehc = (tid & 3) * 4;
        const int hcg = j * 16 + ehc;
        f32x4 wb[4];
#pragma unroll
        for (int q = 0; q < 4; ++q) wb[q] = *(const f32x4*)(a.Wb[q] + hcg);
        f32x4 c = *(const f32x4*)(a.c0 + (size_t)eb * H_ + hcg);

        for (int t = 0; t < T_; ++t) {
            // prefetch U for this step (h-independent)
            ushort4_t u[4];
#pragma unroll
            for (int q = 0; q < 4; ++q)
                u[q] = *(const ushort4_t*)(a.U[q] + ((size_t)t * B_ + eb) * H_ + hcg);
            // stage full h into LDS (wide cooperative load -> max MLP)
            const unsigned short* hp = t ? (a.Hall + (size_t)(t - 1) * B_ * H_) : a.h0c;
#pragma unroll
            for (int it = 0; it < 16; ++it) {
                int id = it * 256 + tid;
                int row = id >> 6, c8 = (id & 63) * 8;
                ushort8_t v = *(const ushort8_t*)(hp + row * H_ + c8);
                *(ushort8_t*)&hs[row * 520 + c8] = v;
            }
            __syncthreads();
            f32x4 acc[4] = {{0.f,0.f,0.f,0.f},{0.f,0.f,0.f,0.f},{0.f,0.f,0.f,0.f},{0.f,0.f,0.f,0.f}};
#pragma unroll
            for (int kc = 0; kc < 16; ++kc) {
#pragma unroll
                for (int nt = 0; nt < 4; ++nt) {
                    bf16x8 bfr = *(const bf16x8*)&hs[(nt * 16 + l16) * 520 + kc * 32 + quad * 8];
                    acc[nt] = mfma16(afrag[kc], bfr, acc[nt]);
                }
            }
#pragma unroll
            for (int nt = 0; nt < 4; ++nt)
#pragma unroll
                for (int r = 0; r < 4; ++r)
                    xch[g * 1040 + (quad * 4 + r) * 65 + nt * 16 + l16] = acc[nt][r];
            __syncthreads();
            ushort4_t hnew;
#pragma unroll
            for (int r = 0; r < 4; ++r) {
                float pi = xch[0 * 1040 + (ehc + r) * 65 + eb] + b2f(u[0][r]) + wb[0][r];
                float pf = xch[1 * 1040 + (ehc + r) * 65 + eb] + b2f(u[1][r]) + wb[1][r];
                float po = xch[2 * 1040 + (ehc + r) * 65 + eb] + b2f(u[2][r]) + wb[2][r];
                float pc = xch[3 * 1040 + (ehc + r) * 65 + eb] + b2f(u[3][r]) + wb[3][r];
                float it = 1.f / (1.f + __expf(-pi));
                float ft = 1.f / (1.f + __expf(-pf));
                float ot = 1.f / (1.f + __expf(-po));
                float ct = tanhf(pc);
                float cn = ft * c[r] + it * ct;
                c[r] = cn;
                hnew[r] = f2b(ot * cn);
            }
            {
                union { ushort4_t s4; unsigned long long q; } hu;
                hu.s4 = hnew;
                __hip_atomic_store((unsigned long long*)(a.Hall + ((size_t)t * B_ + eb) * H_ + hcg),
                                   hu.q, __ATOMIC_RELAXED, __HIP_MEMORY_SCOPE_AGENT);
            }
            asm volatile("s_waitcnt vmcnt(0)" ::: "memory");
            __syncthreads();   // all waves' h stores drained
            if (tid == 0)
                __hip_atomic_store(&a.bar[j * 32], t + 1, __ATOMIC_RELAXED, __HIP_MEMORY_SCOPE_AGENT);
            // direct 32-line poll (latency path, 32 low-duty pollers only);
            // WG0 additionally publishes the aggregated epoch flag for the 224
            // projection WGs, so their poll storm never touches the per-WG lines.
            if (t + 1 < T_ || j == 0) {
                if (g == 0) {
                    const int fi = (lane & 31) * 32;
                    bool done;
                    do {
                        int v = __hip_atomic_load(&a.bar[fi], __ATOMIC_RELAXED, __HIP_MEMORY_SCOPE_AGENT);
                        done = __all(v >= t + 1);
                        if (!done) __builtin_amdgcn_s_sleep(1);
                    } while (!done);
                    if (j == 0 && lane == 0)
                        __hip_atomic_store(&a.bar[AGGF_], t + 1, __ATOMIC_RELAXED, __HIP_MEMORY_SCOPE_AGENT);
                }
                if (t + 1 < T_) __syncthreads();
            }
        }
    } else {
        // -------- projection WG: 64x128 tiles of d_out, gated on aggregated flag.
        // n-major chunked job order: job = n_tile*T + t, each WG owns a contiguous
        // chunk -> consecutive jobs share the same Ct n-tile (L2-resident reuse,
        // ~7x less L3 Ct traffic vs t-major). Poll only when t increases (bar is
        // monotone, so t below the high-water mark needs no gate).
        unsigned short* As = (unsigned short*)pool;              // 64 x 136
        unsigned short* Bs = (unsigned short*)(pool + 17408);    // 128 x 136
        const int wv = tid >> 6;
        const int mw = (wv & 1) * 32, nw = (wv >> 1) * 64;
        const int NJ = T_ * NTN_;
        const int w = (int)blockIdx.x - NR_;
        const int qs = w * NJ / NPW_;
        const int qe = (w + 1) * NJ / NPW_;
        int hiT = -1;   // high-water mark of observed recurrence progress
        for (int q = qs; q < qe; ++q) {
            const int t = q % T_, n0 = (q / T_) * 128;
            if (t > hiT) {
                if (tid < 64) {   // one wave polls ONE isolated line
                    while (__hip_atomic_load(&a.bar[AGGF_], __ATOMIC_RELAXED, __HIP_MEMORY_SCOPE_AGENT) < t + 1)
                        __builtin_amdgcn_s_sleep(8);
                }
                __syncthreads();
                hiT = t;
            }
            const unsigned short* Ap = a.Hall + (size_t)t * B_ * H_;
            f32x4 acc[2][4] = {};
            for (int k0 = 0; k0 < H_; k0 += 128) {
                // stage A 64x128 (stride 136) + B 128x128 (stride 136)
                {
                    int id = tid;
#pragma unroll
                    for (int it = 0; it < 4; ++it, id += 256) {
                        int row = id >> 4, c8 = (id & 15) * 8;
                        *(ushort8_t*)&As[row * 136 + c8] =
                            *(const ushort8_t*)(Ap + (size_t)row * H_ + k0 + c8);
                    }
                    int id2 = tid;
#pragma unroll
                    for (int it = 0; it < 8; ++it, id2 += 256) {
                        int row = id2 >> 4, c8 = (id2 & 15) * 8;
                        int gn = n0 + row;
                        ushort8_t v = {0, 0, 0, 0, 0, 0, 0, 0};
                        if (gn < V_) v = *(const ushort8_t*)(a.Ct + (size_t)gn * H_ + k0 + c8);
                        *(ushort8_t*)&Bs[row * 136 + c8] = v;
                    }
                }
                __syncthreads();
#pragma unroll
                for (int kk = 0; kk < 4; ++kk) {
                    bf16x8 af[2], bf[4];
#pragma unroll
                    for (int mt = 0; mt < 2; ++mt)
                        af[mt] = *(const bf16x8*)&As[(mw + mt * 16 + l16) * 136 + kk * 32 + quad * 8];
#pragma unroll
                    for (int nt = 0; nt < 4; ++nt)
                        bf[nt] = *(const bf16x8*)&Bs[(nw + nt * 16 + l16) * 136 + kk * 32 + quad * 8];
#pragma unroll
                    for (int mt = 0; mt < 2; ++mt)
#pragma unroll
                        for (int nt = 0; nt < 4; ++nt)
                            acc[mt][nt] = mfma16(af[mt], bf[nt], acc[mt][nt]);
                }
                __syncthreads();
            }
#pragma unroll
            for (int mt = 0; mt < 2; ++mt)
#pragma unroll
                for (int nt = 0; nt < 4; ++nt) {
                    int col = n0 + nw + nt * 16 + l16;
                    if (col >= V_) continue;
                    float bv = a.Cb[col];
                    int bb = mw + mt * 16 + quad * 4;
#pragma unroll
                    for (int r = 0; r < 4; ++r) {
                        int orow = (bb + r) * T_ + t;
                        a.out[(size_t)orow * V_ + col] = acc[mt][nt][r] + bv;
                    }
                }
        }
    }
}

extern "C" void kernel_launch(void* const* d_in, const int* in_sizes, int n_in,
                              void* d_out, int out_size, void* d_ws, size_t ws_size,
                              hipStream_t stream) {
    (void)in_sizes; (void)n_in; (void)out_size; (void)ws_size;
    const int* captions = (const int*)d_in[0];
    const float* features = (const float*)d_in[1];
    const float* h0 = (const float*)d_in[2];
    const float* c0 = (const float*)d_in[3];
    const float* Bemb = (const float*)d_in[4];
    const float *iVW[4], *iVb[4], *iSW[4], *iSb[4], *iUW[4], *iUb[4], *iWW[4], *iWb[4];
    for (int g = 0; g < 4; ++g) {
        const int base = 5 + 8 * g;
        iVW[g] = (const float*)d_in[base + 0];
        iVb[g] = (const float*)d_in[base + 1];
        iSW[g] = (const float*)d_in[base + 2];
        iSb[g] = (const float*)d_in[base + 3];
        iUW[g] = (const float*)d_in[base + 4];
        iUb[g] = (const float*)d_in[base + 5];
        iWW[g] = (const float*)d_in[base + 6];
        iWb[g] = (const float*)d_in[base + 7];
    }
    const float* CW = (const float*)d_in[37];
    const float* Cb = (const float*)d_in[38];

    char* w = (char*)d_ws;
    auto alloc = [&](size_t bytes) -> void* {
        void* p = (void*)w;
        w += (bytes + 255) & ~(size_t)255;
        return p;
    };
    int* dbar = (int*)alloc(8192);   // 32 flag lines (0..4095) + isolated AGGF line
    unsigned short* cH0 = (unsigned short*)alloc((size_t)B_ * H_ * 2);
    unsigned short *wVt[4], *wSt[4], *wUt[4], *wWt[4];
    for (int g = 0; g < 4; ++g) wVt[g] = (unsigned short*)alloc((size_t)FD_ * 320 * 2);
    for (int g = 0; g < 4; ++g) wSt[g] = (unsigned short*)alloc((size_t)FD_ * FD_ * 2);
    for (int g = 0; g < 4; ++g) wUt[g] = (unsigned short*)alloc((size_t)H_ * FD_ * 2);
    for (int g = 0; g < 4; ++g) wWt[g] = (unsigned short*)alloc((size_t)H_ * H_ * 2);
    unsigned short* wCt = (unsigned short*)alloc((size_t)V_ * H_ * 2);
    unsigned short* wX = (unsigned short*)alloc((size_t)B_ * T_ * 304 * 2);
    unsigned short* bufA[4];
    for (int g = 0; g < 4; ++g) bufA[g] = (unsigned short*)alloc((size_t)B_ * T_ * FD_ * 2);
    unsigned short* Hall = (unsigned short*)alloc((size_t)B_ * T_ * H_ * 2);

    // ---- dispatch 1: prep (transposes + build_x + h0 + flags)
    {
        PrepA p{};
        for (int g = 0; g < 4; ++g) {
            p.tsrc[g * 3 + 0] = iSW[g]; p.tdst[g * 3 + 0] = wSt[g];
            p.tsrc[g * 3 + 1] = iUW[g]; p.tdst[g * 3 + 1] = wUt[g];
            p.tsrc[g * 3 + 2] = iWW[g]; p.tdst[g * 3 + 2] = wWt[g];
            p.tsrc[12 + g] = iVW[g];    p.tdst[12 + g] = wVt[g];
        }
        p.tsrc[16] = CW; p.tdst[16] = wCt;
        p.captions = captions; p.features = features; p.Bemb = Bemb; p.X = wX;
        p.h0 = h0; p.cH0 = cH0; p.bar = dbar;
        prep_k<<<dim3(11128), 256, 0, stream>>>(p);
    }

    // ---- dispatch 2: fused 3-stage chain
    {
        ChainA ca{};
        ca.X = wX;
        for (int g = 0; g < 4; ++g) {
            ca.Vt[g] = wVt[g]; ca.Vb[g] = iVb[g];
            ca.St[g] = wSt[g]; ca.Sb[g] = iSb[g];
            ca.Ut[g] = wUt[g]; ca.Ub[g] = iUb[g];
            ca.U[g] = bufA[g];
        }
        chain_k<<<dim3(120), 256, 0, stream>>>(ca);
    }

    // ---- dispatch 3: mega (recurrence + overlapped projection)
    {
        MegaA ma{};
        ma.h0c = cH0;
        for (int g = 0; g < 4; ++g) {
            ma.Wt[g] = wWt[g]; ma.Wb[g] = iWb[g]; ma.U[g] = bufA[g];
        }
        ma.c0 = c0;
        ma.Hall = Hall;
        ma.bar = dbar;
        ma.Ct = wCt;
        ma.Cb = Cb;
        ma.out = (float*)d_out;
        mega_k<<<dim3(NR_ + NPW_), 256, 0, stream>>>(ma);
    }
}

// Round 8
// 449.694 us; speedup vs baseline: 1.2159x; 1.2159x over previous
//
#include <hip/hip_runtime.h>
#include <hip/hip_bf16.h>

#define B_  64
#define T_  30
#define E_  300
#define H_  512
#define FD_ 512
#define V_  10000
#define NR_ 32          // recurrence WGs
#define NPW_ 224        // projection WGs
#define NTN_ 79         // N tiles of 128 covering V=10000
#define NTG_ 8          // t-groups of 4 covering T=30 (last group has 2)
#define AGGF_ 1056      // aggregated epoch flag: byte 4224, own cache line
// bar[0] = cumulative rec step counter (32 adds per step, value 32*(t+1) when step t done)

typedef __attribute__((ext_vector_type(8))) unsigned short ushort8_t;
typedef __attribute__((ext_vector_type(4))) unsigned short ushort4_t;
typedef __attribute__((ext_vector_type(8))) __bf16 bf16x8;
typedef __attribute__((ext_vector_type(4))) float f32x4;

__device__ __forceinline__ float b2f(unsigned short u) {
    union { unsigned int i; float f; } v;
    v.i = ((unsigned int)u) << 16;
    return v.f;
}
__device__ __forceinline__ unsigned short f2b(float f) {
    unsigned int x = __builtin_bit_cast(unsigned int, f);
    unsigned int r = x + 0x7FFFu + ((x >> 16) & 1u);
    return (unsigned short)(r >> 16);
}
__device__ __forceinline__ f32x4 mfma16(bf16x8 a, bf16x8 b, f32x4 c) {
    return __builtin_amdgcn_mfma_f32_16x16x32_bf16(a, b, c, 0, 0, 0);
}

// ================= prep: all transposes + build_x + h0 conv + flag zero =================
struct PrepA {
    const float* tsrc[17];
    unsigned short* tdst[17];
    const int* captions;
    const float* features;
    const float* Bemb;
    unsigned short* X;          // stride 304
    const float* h0;
    unsigned short* cH0;
    int* bar;
};

__global__ __launch_bounds__(256) void prep_k(PrepA p) {
    const int blk = blockIdx.x, tid = threadIdx.x;
    __shared__ unsigned short tile[32][33];
    if (blk < 8720) {
        int z, bx, by, R, C, Rpad, ld;
        if (blk < 3072) { z = blk >> 8; int wq = blk & 255; bx = wq & 15; by = wq >> 4; R = 512; C = 512; Rpad = 512; ld = 512; }
        else if (blk < 3712) { int b2 = blk - 3072; z = 12 + b2 / 160; int wq = b2 % 160; bx = wq & 15; by = wq >> 4; R = 300; C = 512; Rpad = 320; ld = 320; }
        else { int b2 = blk - 3712; z = 16; bx = b2 % 313; by = b2 / 313; R = 512; C = 10000; Rpad = 512; ld = 512; }
        const float* __restrict__ src = p.tsrc[z];
        unsigned short* __restrict__ dst = p.tdst[z];
        const int tc = tid & 31, tr = tid >> 5;
        const int c0 = bx * 32, r0 = by * 32;
#pragma unroll
        for (int i = 0; i < 4; ++i) {
            int r = r0 + tr + i * 8, c = c0 + tc;
            unsigned short v = 0;
            if (r < R && c < C) v = f2b(src[(size_t)r * C + c]);
            tile[tr + i * 8][tc] = v;
        }
        __syncthreads();
#pragma unroll
        for (int i = 0; i < 4; ++i) {
            int c = c0 + tr + i * 8;
            int r = r0 + tc;
            if (c < C && r < Rpad) dst[(size_t)c * ld + r] = tile[tc][tr + i * 8];
        }
    } else if (blk < 11000) {
        int idx = (blk - 8720) * 256 + tid;          // over B*T*304
        if (idx < B_ * T_ * 304) {
            int r = idx / 304, e = idx - r * 304;
            int t = r >> 6, b = r & 63;
            float v = 0.f;
            if (e < E_) {
                if (t == 0) v = p.features[b * E_ + e];
                else {
                    int tok = p.captions[b * T_ + (t - 1)];
                    v = p.Bemb[(size_t)tok * E_ + e];
                }
            }
            p.X[(size_t)r * 304 + e] = f2b(v);
        }
    } else {
        int i = (blk - 11000) * 256 + tid;           // 128 blocks -> 32768 threads
        if (i < 2048) p.bar[i] = 0;                  // counter + AGGF lines
        if (i < B_ * H_) p.cH0[i] = f2b(p.h0[i]);
    }
}

// ================= chain: fused 3-stage gate preactivation =================
struct ChainA {
    const unsigned short* X;      // [1920][304]
    const unsigned short* Vt[4];  // [512][320] (zero-padded K)
    const float* Vb[4];
    const unsigned short* St[4];  // [512][512]
    const float* Sb[4];
    const unsigned short* Ut[4];  // [512][512]
    const float* Ub[4];
    unsigned short* U[4];         // out [1920][512] bf16
};

__global__ __launch_bounds__(256) void chain_k(ChainA ca) {
    const int rb = blockIdx.x >> 2, g = blockIdx.x & 3;
    __shared__ char pool[133120];
    unsigned short* XT = (unsigned short*)pool;             // stage A in, stride 328
    unsigned short* R0 = (unsigned short*)pool;             // stage B out, stride 520
    unsigned short* R1 = (unsigned short*)(pool + 66560);   // stage A out, stride 520
    const int tid = threadIdx.x;
    const int wv = tid >> 6, lane = tid & 63;
    const int quad = lane >> 4, l16 = lane & 15;

    {
        const unsigned short* src = ca.X + (size_t)rb * 64 * 304;
#pragma unroll
        for (int it = 0; it < 10; ++it) {
            int id = it * 256 + tid;                        // 2560 chunks of 8
            int row = id / 40, c8 = (id % 40) * 8;
            ushort8_t v = {0, 0, 0, 0, 0, 0, 0, 0};
            if (c8 < 304) v = *(const ushort8_t*)(src + row * 304 + c8);
            *(ushort8_t*)&XT[row * 328 + c8] = v;
        }
    }
    __syncthreads();
    // ---- stage A: R1 = X @ Vt^T + Vb  (K=320 padded)
#pragma unroll
    for (int half = 0; half < 2; ++half) {
        const int cb = wv * 128 + half * 64;
        f32x4 acc[4][4] = {};
        for (int kc = 0; kc < 10; ++kc) {
            bf16x8 af[4];
#pragma unroll
            for (int mt = 0; mt < 4; ++mt)
                af[mt] = *(const bf16x8*)&XT[(mt * 16 + l16) * 328 + kc * 32 + quad * 8];
#pragma unroll
            for (int nt = 0; nt < 4; ++nt) {
                bf16x8 bf = *(const bf16x8*)(ca.Vt[g] + (size_t)(cb + nt * 16 + l16) * 320 + kc * 32 + quad * 8);
#pragma unroll
                for (int mt = 0; mt < 4; ++mt) acc[mt][nt] = mfma16(af[mt], bf, acc[mt][nt]);
            }
        }
#pragma unroll
        for (int mt = 0; mt < 4; ++mt)
#pragma unroll
            for (int nt = 0; nt < 4; ++nt) {
                int col = cb + nt * 16 + l16;
                float bv = ca.Vb[g][col];
#pragma unroll
                for (int r = 0; r < 4; ++r)
                    R1[(mt * 16 + quad * 4 + r) * 520 + col] = f2b(acc[mt][nt][r] + bv);
            }
    }
    __syncthreads();
    // ---- stage B: R0 = R1 @ St^T + Sb  (K=512)
#pragma unroll
    for (int half = 0; half < 2; ++half) {
        const int cb = wv * 128 + half * 64;
        f32x4 acc[4][4] = {};
        for (int kc = 0; kc < 16; ++kc) {
            bf16x8 af[4];
#pragma unroll
            for (int mt = 0; mt < 4; ++mt)
                af[mt] = *(const bf16x8*)&R1[(mt * 16 + l16) * 520 + kc * 32 + quad * 8];
#pragma unroll
            for (int nt = 0; nt < 4; ++nt) {
                bf16x8 bf = *(const bf16x8*)(ca.St[g] + (size_t)(cb + nt * 16 + l16) * 512 + kc * 32 + quad * 8);
#pragma unroll
                for (int mt = 0; mt < 4; ++mt) acc[mt][nt] = mfma16(af[mt], bf, acc[mt][nt]);
            }
        }
        __syncthreads();   // R0 aliases XT region; ensure pool reads done before overwrite
#pragma unroll
        for (int mt = 0; mt < 4; ++mt)
#pragma unroll
            for (int nt = 0; nt < 4; ++nt) {
                int col = cb + nt * 16 + l16;
                float bv = ca.Sb[g][col];
#pragma unroll
                for (int r = 0; r < 4; ++r)
                    R0[(mt * 16 + quad * 4 + r) * 520 + col] = f2b(acc[mt][nt][r] + bv);
            }
    }
    __syncthreads();
    // ---- stage C: global U = R0 @ Ut^T + Ub
#pragma unroll
    for (int half = 0; half < 2; ++half) {
        const int cb = wv * 128 + half * 64;
        f32x4 acc[4][4] = {};
        for (int kc = 0; kc < 16; ++kc) {
            bf16x8 af[4];
#pragma unroll
            for (int mt = 0; mt < 4; ++mt)
                af[mt] = *(const bf16x8*)&R0[(mt * 16 + l16) * 520 + kc * 32 + quad * 8];
#pragma unroll
            for (int nt = 0; nt < 4; ++nt) {
                bf16x8 bf = *(const bf16x8*)(ca.Ut[g] + (size_t)(cb + nt * 16 + l16) * 512 + kc * 32 + quad * 8);
#pragma unroll
                for (int mt = 0; mt < 4; ++mt) acc[mt][nt] = mfma16(af[mt], bf, acc[mt][nt]);
            }
        }
#pragma unroll
        for (int mt = 0; mt < 4; ++mt)
#pragma unroll
            for (int nt = 0; nt < 4; ++nt) {
                int col = cb + nt * 16 + l16;
                float bv = ca.Ub[g][col];
#pragma unroll
                for (int r = 0; r < 4; ++r)
                    ca.U[g][(size_t)(rb * 64 + mt * 16 + quad * 4 + r) * 512 + col] =
                        f2b(acc[mt][nt][r] + bv);
            }
    }
}

// ================= mega: recurrence (32 WGs) + flag-gated projection (224 WGs) =================
struct MegaA {
    const unsigned short* h0c;    // [B][H] bf16
    const unsigned short* Wt[4];  // [512][512]
    const float* Wb[4];
    const unsigned short* U[4];   // [1920][512] bf16
    const float* c0;              // f32
    unsigned short* Hall;         // [1920][512] bf16
    int* bar;                     // [0]=step counter, [AGGF_]=epoch for projection
    const unsigned short* Ct;     // [10000][512] bf16
    const float* Cb;
    float* out;                   // [B][T][V] f32
};

__global__ __launch_bounds__(256, 1) void mega_k(MegaA a) {
    __shared__ char pool[83712];
    const int tid = threadIdx.x;
    const int lane = tid & 63;
    const int quad = lane >> 4, l16 = lane & 15;

    if (blockIdx.x < NR_) {
        // -------- recurrence WG: owns h-cols [j*16, j*16+16), wave g = gate
        unsigned short* hs = (unsigned short*)pool;       // 64 x 520
        float* xch = (float*)(pool + 66560);              // [4][16*65]
        const int j = blockIdx.x;
        const int g = tid >> 6;
        bf16x8 afrag[16];
        {
            const unsigned short* wt = a.Wt[g] + (size_t)(j * 16 + l16) * H_ + quad * 8;
#pragma unroll
            for (int kc = 0; kc < 16; ++kc) afrag[kc] = *(const bf16x8*)(wt + kc * 32);
        }
        const int eb = tid >> 2;
        const int ehc = (tid & 3) * 4;
        const int hcg = j * 16 + ehc;
        f32x4 wb[4];
#pragma unroll
        for (int q = 0; q < 4; ++q) wb[q] = *(const f32x4*)(a.Wb[q] + hcg);
        f32x4 c = *(const f32x4*)(a.c0 + (size_t)eb * H_ + hcg);

        for (int t = 0; t < T_; ++t) {
            // prefetch U for this step (h-independent)
            ushort4_t u[4];
#pragma unroll
            for (int q = 0; q < 4; ++q)
                u[q] = *(const ushort4_t*)(a.U[q] + ((size_t)t * B_ + eb) * H_ + hcg);
            // stage full h into LDS (wide cooperative load -> max MLP)
            const unsigned short* hp = t ? (a.Hall + (size_t)(t - 1) * B_ * H_) : a.h0c;
#pragma unroll
            for (int it = 0; it < 16; ++it) {
                int id = it * 256 + tid;
                int row = id >> 6, c8 = (id & 63) * 8;
                ushort8_t v = *(const ushort8_t*)(hp + row * H_ + c8);
                *(ushort8_t*)&hs[row * 520 + c8] = v;
            }
            __syncthreads();
            f32x4 acc[4] = {{0.f,0.f,0.f,0.f},{0.f,0.f,0.f,0.f},{0.f,0.f,0.f,0.f},{0.f,0.f,0.f,0.f}};
#pragma unroll
            for (int kc = 0; kc < 16; ++kc) {
#pragma unroll
                for (int nt = 0; nt < 4; ++nt) {
                    bf16x8 bfr = *(const bf16x8*)&hs[(nt * 16 + l16) * 520 + kc * 32 + quad * 8];
                    acc[nt] = mfma16(afrag[kc], bfr, acc[nt]);
                }
            }
#pragma unroll
            for (int nt = 0; nt < 4; ++nt)
#pragma unroll
                for (int r = 0; r < 4; ++r)
                    xch[g * 1040 + (quad * 4 + r) * 65 + nt * 16 + l16] = acc[nt][r];
            __syncthreads();
            ushort4_t hnew;
#pragma unroll
            for (int r = 0; r < 4; ++r) {
                float pi = xch[0 * 1040 + (ehc + r) * 65 + eb] + b2f(u[0][r]) + wb[0][r];
                float pf = xch[1 * 1040 + (ehc + r) * 65 + eb] + b2f(u[1][r]) + wb[1][r];
                float po = xch[2 * 1040 + (ehc + r) * 65 + eb] + b2f(u[2][r]) + wb[2][r];
                float pc = xch[3 * 1040 + (ehc + r) * 65 + eb] + b2f(u[3][r]) + wb[3][r];
                float it = 1.f / (1.f + __expf(-pi));
                float ft = 1.f / (1.f + __expf(-pf));
                float ot = 1.f / (1.f + __expf(-po));
                float ct = tanhf(pc);
                float cn = ft * c[r] + it * ct;
                c[r] = cn;
                hnew[r] = f2b(ot * cn);
            }
            {
                union { ushort4_t s4; unsigned long long q; } hu;
                hu.s4 = hnew;
                __hip_atomic_store((unsigned long long*)(a.Hall + ((size_t)t * B_ + eb) * H_ + hcg),
                                   hu.q, __ATOMIC_RELAXED, __HIP_MEMORY_SCOPE_AGENT);
            }
            asm volatile("s_waitcnt vmcnt(0)" ::: "memory");
            __syncthreads();   // all waves' h stores drained
            // single cumulative counter barrier: 32 adds/step, done when ctr==32*(t+1).
            // One hot line for adds+rec polls; projection polls only the isolated AGGF
            // line, published by WG0 after it detects step completion.
            if (tid == 0) {
                __hip_atomic_fetch_add(&a.bar[0], 1, __ATOMIC_RELAXED, __HIP_MEMORY_SCOPE_AGENT);
                if (t + 1 < T_ || j == 0) {
                    while (__hip_atomic_load(&a.bar[0], __ATOMIC_RELAXED, __HIP_MEMORY_SCOPE_AGENT) < NR_ * (t + 1))
                        __builtin_amdgcn_s_sleep(1);
                    if (j == 0)
                        __hip_atomic_store(&a.bar[AGGF_], t + 1, __ATOMIC_RELAXED, __HIP_MEMORY_SCOPE_AGENT);
                }
            }
            if (t + 1 < T_) __syncthreads();
        }
    } else {
        // -------- projection WG: t-group batched tiles (G=4 timesteps share one Ct
        // tile load -> Ct traffic /4, staging/step /2). t-major strided job order:
        // job q = tg*NTN + n, WG strides by NPW -> tg non-decreasing per WG.
        // K-chunk 64; B-fragments reused across the 4 t's.
        unsigned short* As = (unsigned short*)pool;              // [4][64][72]
        unsigned short* Bs = (unsigned short*)(pool + 36864);    // [128][72]
        const int wv = tid >> 6;
        const int mw = (wv & 1) * 32, nw = (wv >> 1) * 64;
        const int NJ = NTG_ * NTN_;                              // 632 jobs
        int hiF = 0;   // high-water mark of observed epoch
        for (int q = (int)blockIdx.x - NR_; q < NJ; q += NPW_) {
            const int tg = q / NTN_, n0 = (q % NTN_) * 128;
            const int tb = tg * 4;
            const int need = (tb + 4 < T_) ? tb + 4 : T_;        // epoch required
            if (need > hiF) {
                if (tid < 64) {   // one wave polls the isolated AGGF line
                    while (__hip_atomic_load(&a.bar[AGGF_], __ATOMIC_RELAXED, __HIP_MEMORY_SCOPE_AGENT) < need)
                        __builtin_amdgcn_s_sleep(8);
                }
                __syncthreads();
                hiF = need;
            }
            f32x4 acc[4][2][4] = {};    // [tt][mt][nt], all indexing compile-time
            for (int k0 = 0; k0 < H_; k0 += 64) {
                // stage As: 4 t-slices of 64x64 (clamped to t=29 for tail group)
#pragma unroll
                for (int tt = 0; tt < 4; ++tt) {
                    int tA = tb + tt; if (tA >= T_) tA = T_ - 1;
                    const unsigned short* Ap = a.Hall + (size_t)tA * B_ * H_;
                    int id = tid;
#pragma unroll
                    for (int it = 0; it < 2; ++it, id += 256) {
                        int row = id >> 3, c8 = (id & 7) * 8;
                        *(ushort8_t*)&As[tt * 4608 + row * 72 + c8] =
                            *(const ushort8_t*)(Ap + (size_t)row * H_ + k0 + c8);
                    }
                }
                // stage Bs: 128x64
                {
                    int id2 = tid;
#pragma unroll
                    for (int it = 0; it < 4; ++it, id2 += 256) {
                        int row = id2 >> 3, c8 = (id2 & 7) * 8;
                        int gn = n0 + row;
                        ushort8_t v = {0, 0, 0, 0, 0, 0, 0, 0};
                        if (gn < V_) v = *(const ushort8_t*)(a.Ct + (size_t)gn * H_ + k0 + c8);
                        *(ushort8_t*)&Bs[row * 72 + c8] = v;
                    }
                }
                __syncthreads();
#pragma unroll
                for (int kk = 0; kk < 2; ++kk) {
                    bf16x8 bf[4];
#pragma unroll
                    for (int nt = 0; nt < 4; ++nt)
                        bf[nt] = *(const bf16x8*)&Bs[(nw + nt * 16 + l16) * 72 + kk * 32 + quad * 8];
#pragma unroll
                    for (int tt = 0; tt < 4; ++tt) {
                        bf16x8 af[2];
#pragma unroll
                        for (int mt = 0; mt < 2; ++mt)
                            af[mt] = *(const bf16x8*)&As[tt * 4608 + (mw + mt * 16 + l16) * 72 + kk * 32 + quad * 8];
#pragma unroll
                        for (int mt = 0; mt < 2; ++mt)
#pragma unroll
                            for (int nt = 0; nt < 4; ++nt)
                                acc[tt][mt][nt] = mfma16(af[mt], bf[nt], acc[tt][mt][nt]);
                    }
                }
                __syncthreads();
            }
#pragma unroll
            for (int tt = 0; tt < 4; ++tt) {
                const int t = tb + tt;
                if (t >= T_) continue;
#pragma unroll
                for (int mt = 0; mt < 2; ++mt)
#pragma unroll
                    for (int nt = 0; nt < 4; ++nt) {
                        int col = n0 + nw + nt * 16 + l16;
                        if (col >= V_) continue;
                        float bv = a.Cb[col];
                        int bb = mw + mt * 16 + quad * 4;
#pragma unroll
                        for (int r = 0; r < 4; ++r) {
                            int orow = (bb + r) * T_ + t;
                            a.out[(size_t)orow * V_ + col] = acc[tt][mt][nt][r] + bv;
                        }
                    }
            }
        }
    }
}

extern "C" void kernel_launch(void* const* d_in, const int* in_sizes, int n_in,
                              void* d_out, int out_size, void* d_ws, size_t ws_size,
                              hipStream_t stream) {
    (void)in_sizes; (void)n_in; (void)out_size; (void)ws_size;
    const int* captions = (const int*)d_in[0];
    const float* features = (const float*)d_in[1];
    const float* h0 = (const float*)d_in[2];
    const float* c0 = (const float*)d_in[3];
    const float* Bemb = (const float*)d_in[4];
    const float *iVW[4], *iVb[4], *iSW[4], *iSb[4], *iUW[4], *iUb[4], *iWW[4], *iWb[4];
    for (int g = 0; g < 4; ++g) {
        const int base = 5 + 8 * g;
        iVW[g] = (const float*)d_in[base + 0];
        iVb[g] = (const float*)d_in[base + 1];
        iSW[g] = (const float*)d_in[base + 2];
        iSb[g] = (const float*)d_in[base + 3];
        iUW[g] = (const float*)d_in[base + 4];
        iUb[g] = (const float*)d_in[base + 5];
        iWW[g] = (const float*)d_in[base + 6];
        iWb[g] = (const float*)d_in[base + 7];
    }
    const float* CW = (const float*)d_in[37];
    const float* Cb = (const float*)d_in[38];

    char* w = (char*)d_ws;
    auto alloc = [&](size_t bytes) -> void* {
        void* p = (void*)w;
        w += (bytes + 255) & ~(size_t)255;
        return p;
    };
    int* dbar = (int*)alloc(8192);   // counter line (0) + isolated AGGF line (byte 4224)
    unsigned short* cH0 = (unsigned short*)alloc((size_t)B_ * H_ * 2);
    unsigned short *wVt[4], *wSt[4], *wUt[4], *wWt[4];
    for (int g = 0; g < 4; ++g) wVt[g] = (unsigned short*)alloc((size_t)FD_ * 320 * 2);
    for (int g = 0; g < 4; ++g) wSt[g] = (unsigned short*)alloc((size_t)FD_ * FD_ * 2);
    for (int g = 0; g < 4; ++g) wUt[g] = (unsigned short*)alloc((size_t)H_ * FD_ * 2);
    for (int g = 0; g < 4; ++g) wWt[g] = (unsigned short*)alloc((size_t)H_ * H_ * 2);
    unsigned short* wCt = (unsigned short*)alloc((size_t)V_ * H_ * 2);
    unsigned short* wX = (unsigned short*)alloc((size_t)B_ * T_ * 304 * 2);
    unsigned short* bufA[4];
    for (int g = 0; g < 4; ++g) bufA[g] = (unsigned short*)alloc((size_t)B_ * T_ * FD_ * 2);
    unsigned short* Hall = (unsigned short*)alloc((size_t)B_ * T_ * H_ * 2);

    // ---- dispatch 1: prep (transposes + build_x + h0 + flags)
    {
        PrepA p{};
        for (int g = 0; g < 4; ++g) {
            p.tsrc[g * 3 + 0] = iSW[g]; p.tdst[g * 3 + 0] = wSt[g];
            p.tsrc[g * 3 + 1] = iUW[g]; p.tdst[g * 3 + 1] = wUt[g];
            p.tsrc[g * 3 + 2] = iWW[g]; p.tdst[g * 3 + 2] = wWt[g];
            p.tsrc[12 + g] = iVW[g];    p.tdst[12 + g] = wVt[g];
        }
        p.tsrc[16] = CW; p.tdst[16] = wCt;
        p.captions = captions; p.features = features; p.Bemb = Bemb; p.X = wX;
        p.h0 = h0; p.cH0 = cH0; p.bar = dbar;
        prep_k<<<dim3(11128), 256, 0, stream>>>(p);
    }

    // ---- dispatch 2: fused 3-stage chain
    {
        ChainA ca{};
        ca.X = wX;
        for (int g = 0; g < 4; ++g) {
            ca.Vt[g] = wVt[g]; ca.Vb[g] = iVb[g];
            ca.St[g] = wSt[g]; ca.Sb[g] = iSb[g];
            ca.Ut[g] = wUt[g]; ca.Ub[g] = iUb[g];
            ca.U[g] = bufA[g];
        }
        chain_k<<<dim3(120), 256, 0, stream>>>(ca);
    }

    // ---- dispatch 3: mega (recurrence + overlapped projection)
    {
        MegaA ma{};
        ma.h0c = cH0;
        for (int g = 0; g < 4; ++g) {
            ma.Wt[g] = wWt[g]; ma.Wb[g] = iWb[g]; ma.U[g] = bufA[g];
        }
        ma.c0 = c0;
        ma.Hall = Hall;
        ma.bar = dbar;
        ma.Ct = wCt;
        ma.Cb = Cb;
        ma.out = (float*)d_out;
        mega_k<<<dim3(NR_ + NPW_), 256, 0, stream>>>(ma);
    }
}

// Round 10
// 413.888 us; speedup vs baseline: 1.3211x; 1.0865x over previous
//
#include <hip/hip_runtime.h>
#include <hip/hip_bf16.h>

#define B_  64
#define T_  30
#define E_  300
#define H_  512
#define FD_ 512
#define V_  10000
#define NR_ 32          // recurrence WGs
#define NPW_ 224        // projection WGs
#define NTN_ 79         // N tiles of 128 covering V=10000
#define NTG_ 8          // t-groups of 4 covering T=30 (last group has 2)
#define AGGF_ 1056      // aggregated epoch flag: byte 4224, own cache line
// bar[0..31]: per-WG step flags packed in ONE 128B line (distinct words -> parallel
// far-writes merge at L3, no serialization; poll = 1 line fetch via bar[lane&31]).

typedef __attribute__((ext_vector_type(8))) unsigned short ushort8_t;
typedef __attribute__((ext_vector_type(4))) unsigned short ushort4_t;
typedef __attribute__((ext_vector_type(8))) __bf16 bf16x8;
typedef __attribute__((ext_vector_type(4))) float f32x4;

__device__ __forceinline__ float b2f(unsigned short u) {
    union { unsigned int i; float f; } v;
    v.i = ((unsigned int)u) << 16;
    return v.f;
}
__device__ __forceinline__ unsigned short f2b(float f) {
    unsigned int x = __builtin_bit_cast(unsigned int, f);
    unsigned int r = x + 0x7FFFu + ((x >> 16) & 1u);
    return (unsigned short)(r >> 16);
}
__device__ __forceinline__ f32x4 mfma16(bf16x8 a, bf16x8 b, f32x4 c) {
    return __builtin_amdgcn_mfma_f32_16x16x32_bf16(a, b, c, 0, 0, 0);
}

// ================= prep: all transposes + build_x + h0 conv + flag zero =================
struct PrepA {
    const float* tsrc[17];
    unsigned short* tdst[17];
    const int* captions;
    const float* features;
    const float* Bemb;
    unsigned short* X;          // stride 304
    const float* h0;
    unsigned short* cH0;
    int* bar;
};

__global__ __launch_bounds__(256) void prep_k(PrepA p) {
    const int blk = blockIdx.x, tid = threadIdx.x;
    __shared__ unsigned short tile[32][33];
    if (blk < 8720) {
        int z, bx, by, R, C, Rpad, ld;
        if (blk < 3072) { z = blk >> 8; int wq = blk & 255; bx = wq & 15; by = wq >> 4; R = 512; C = 512; Rpad = 512; ld = 512; }
        else if (blk < 3712) { int b2 = blk - 3072; z = 12 + b2 / 160; int wq = b2 % 160; bx = wq & 15; by = wq >> 4; R = 300; C = 512; Rpad = 320; ld = 320; }
        else { int b2 = blk - 3712; z = 16; bx = b2 % 313; by = b2 / 313; R = 512; C = 10000; Rpad = 512; ld = 512; }
        const float* __restrict__ src = p.tsrc[z];
        unsigned short* __restrict__ dst = p.tdst[z];
        const int tc = tid & 31, tr = tid >> 5;
        const int c0 = bx * 32, r0 = by * 32;
#pragma unroll
        for (int i = 0; i < 4; ++i) {
            int r = r0 + tr + i * 8, c = c0 + tc;
            unsigned short v = 0;
            if (r < R && c < C) v = f2b(src[(size_t)r * C + c]);
            tile[tr + i * 8][tc] = v;
        }
        __syncthreads();
#pragma unroll
        for (int i = 0; i < 4; ++i) {
            int c = c0 + tr + i * 8;
            int r = r0 + tc;
            if (c < C && r < Rpad) dst[(size_t)c * ld + r] = tile[tc][tr + i * 8];
        }
    } else if (blk < 11000) {
        int idx = (blk - 8720) * 256 + tid;          // over B*T*304
        if (idx < B_ * T_ * 304) {
            int r = idx / 304, e = idx - r * 304;
            int t = r >> 6, b = r & 63;
            float v = 0.f;
            if (e < E_) {
                if (t == 0) v = p.features[b * E_ + e];
                else {
                    int tok = p.captions[b * T_ + (t - 1)];
                    v = p.Bemb[(size_t)tok * E_ + e];
                }
            }
            p.X[(size_t)r * 304 + e] = f2b(v);
        }
    } else {
        int i = (blk - 11000) * 256 + tid;           // 128 blocks -> 32768 threads
        if (i < 2048) p.bar[i] = 0;                  // flag line + AGGF line
        if (i < B_ * H_) p.cH0[i] = f2b(p.h0[i]);
    }
}

// ================= chain: fused 3-stage gate preactivation =================
// 240 WGs (60 rowblocks x 4 gates), 32 rows/WG, 66.5KB LDS -> 2 WGs/CU (was 120 WGs
// x 133KB = 1 WG/CU on half the GPU): full CU coverage + 2x latency hiding.
struct ChainA {
    const unsigned short* X;      // [1920][304]
    const unsigned short* Vt[4];  // [512][320] (zero-padded K)
    const float* Vb[4];
    const unsigned short* St[4];  // [512][512]
    const float* Sb[4];
    const unsigned short* Ut[4];  // [512][512]
    const float* Ub[4];
    unsigned short* U[4];         // out [1920][512] bf16
};

__global__ __launch_bounds__(256) void chain_k(ChainA ca) {
    const int rb = blockIdx.x >> 2, g = blockIdx.x & 3;
    __shared__ char pool[66560];
    unsigned short* XT = (unsigned short*)pool;             // stage A in, stride 328 (20992B)
    unsigned short* R0 = (unsigned short*)pool;             // stage B out, stride 520
    unsigned short* R1 = (unsigned short*)(pool + 33280);   // stage A out, stride 520
    const int tid = threadIdx.x;
    const int wv = tid >> 6, lane = tid & 63;
    const int quad = lane >> 4, l16 = lane & 15;

    {
        const unsigned short* src = ca.X + (size_t)rb * 32 * 304;
#pragma unroll
        for (int it = 0; it < 5; ++it) {
            int id = it * 256 + tid;                        // 1280 chunks of 8
            int row = id / 40, c8 = (id % 40) * 8;
            ushort8_t v = {0, 0, 0, 0, 0, 0, 0, 0};
            if (c8 < 304) v = *(const ushort8_t*)(src + row * 304 + c8);
            *(ushort8_t*)&XT[row * 328 + c8] = v;
        }
    }
    __syncthreads();
    // ---- stage A: R1 = X @ Vt^T + Vb  (K=320 padded)
#pragma unroll
    for (int half = 0; half < 2; ++half) {
        const int cb = wv * 128 + half * 64;
        f32x4 acc[2][4] = {};
        for (int kc = 0; kc < 10; ++kc) {
            bf16x8 af[2];
#pragma unroll
            for (int mt = 0; mt < 2; ++mt)
                af[mt] = *(const bf16x8*)&XT[(mt * 16 + l16) * 328 + kc * 32 + quad * 8];
#pragma unroll
            for (int nt = 0; nt < 4; ++nt) {
                bf16x8 bf = *(const bf16x8*)(ca.Vt[g] + (size_t)(cb + nt * 16 + l16) * 320 + kc * 32 + quad * 8);
#pragma unroll
                for (int mt = 0; mt < 2; ++mt) acc[mt][nt] = mfma16(af[mt], bf, acc[mt][nt]);
            }
        }
#pragma unroll
        for (int mt = 0; mt < 2; ++mt)
#pragma unroll
            for (int nt = 0; nt < 4; ++nt) {
                int col = cb + nt * 16 + l16;
                float bv = ca.Vb[g][col];
#pragma unroll
                for (int r = 0; r < 4; ++r)
                    R1[(mt * 16 + quad * 4 + r) * 520 + col] = f2b(acc[mt][nt][r] + bv);
            }
    }
    __syncthreads();
    // ---- stage B: R0 = R1 @ St^T + Sb  (K=512)
#pragma unroll
    for (int half = 0; half < 2; ++half) {
        const int cb = wv * 128 + half * 64;
        f32x4 acc[2][4] = {};
        for (int kc = 0; kc < 16; ++kc) {
            bf16x8 af[2];
#pragma unroll
            for (int mt = 0; mt < 2; ++mt)
                af[mt] = *(const bf16x8*)&R1[(mt * 16 + l16) * 520 + kc * 32 + quad * 8];
#pragma unroll
            for (int nt = 0; nt < 4; ++nt) {
                bf16x8 bf = *(const bf16x8*)(ca.St[g] + (size_t)(cb + nt * 16 + l16) * 512 + kc * 32 + quad * 8);
#pragma unroll
                for (int mt = 0; mt < 2; ++mt) acc[mt][nt] = mfma16(af[mt], bf, acc[mt][nt]);
            }
        }
        __syncthreads();   // R0 aliases XT region; ensure pool reads done before overwrite
#pragma unroll
        for (int mt = 0; mt < 2; ++mt)
#pragma unroll
            for (int nt = 0; nt < 4; ++nt) {
                int col = cb + nt * 16 + l16;
                float bv = ca.Sb[g][col];
#pragma unroll
                for (int r = 0; r < 4; ++r)
                    R0[(mt * 16 + quad * 4 + r) * 520 + col] = f2b(acc[mt][nt][r] + bv);
            }
    }
    __syncthreads();
    // ---- stage C: global U = R0 @ Ut^T + Ub
#pragma unroll
    for (int half = 0; half < 2; ++half) {
        const int cb = wv * 128 + half * 64;
        f32x4 acc[2][4] = {};
        for (int kc = 0; kc < 16; ++kc) {
            bf16x8 af[2];
#pragma unroll
            for (int mt = 0; mt < 2; ++mt)
                af[mt] = *(const bf16x8*)&R0[(mt * 16 + l16) * 520 + kc * 32 + quad * 8];
#pragma unroll
            for (int nt = 0; nt < 4; ++nt) {
                bf16x8 bf = *(const bf16x8*)(ca.Ut[g] + (size_t)(cb + nt * 16 + l16) * 512 + kc * 32 + quad * 8);
#pragma unroll
                for (int mt = 0; mt < 2; ++mt) acc[mt][nt] = mfma16(af[mt], bf, acc[mt][nt]);
            }
        }
#pragma unroll
        for (int mt = 0; mt < 2; ++mt)
#pragma unroll
            for (int nt = 0; nt < 4; ++nt) {
                int col = cb + nt * 16 + l16;
                float bv = ca.Ub[g][col];
#pragma unroll
                for (int r = 0; r < 4; ++r)
                    ca.U[g][(size_t)(rb * 32 + mt * 16 + quad * 4 + r) * 512 + col] =
                        f2b(acc[mt][nt][r] + bv);
            }
    }
}

// ================= mega: recurrence (32 WGs) + flag-gated projection (224 WGs) =================
struct MegaA {
    const unsigned short* h0c;    // [B][H] bf16
    const unsigned short* Wt[4];  // [512][512]
    const float* Wb[4];
    const unsigned short* U[4];   // [1920][512] bf16
    const float* c0;              // f32
    unsigned short* Hall;         // [1920][512] bf16
    int* bar;                     // [0..31]=flags (1 line), [AGGF_]=epoch (own line)
    const unsigned short* Ct;     // [10000][512] bf16
    const float* Cb;
    float* out;                   // [B][T][V] f32
};

__global__ __launch_bounds__(256, 1) void mega_k(MegaA a) {
    __shared__ char pool[83712];
    const int tid = threadIdx.x;
    const int lane = tid & 63;
    const int quad = lane >> 4, l16 = lane & 15;

    if (blockIdx.x < NR_) {
        // -------- recurrence WG: owns h-cols [j*16, j*16+16), wave g = gate
        unsigned short* hs = (unsigned short*)pool;       // 64 x 520
        float* xch = (float*)(pool + 66560);              // [4][16*65]
        const int j = blockIdx.x;
        const int g = tid >> 6;
        bf16x8 afrag[16];
        {
            const unsigned short* wt = a.Wt[g] + (size_t)(j * 16 + l16) * H_ + quad * 8;
#pragma unroll
            for (int kc = 0; kc < 16; ++kc) afrag[kc] = *(const bf16x8*)(wt + kc * 32);
        }
        const int eb = tid >> 2;
        const int ehc = (tid & 3) * 4;
        const int hcg = j * 16 + ehc;
        f32x4 wb[4];
#pragma unroll
        for (int q = 0; q < 4; ++q) wb[q] = *(const f32x4*)(a.Wb[q] + hcg);
        f32x4 c = *(const f32x4*)(a.c0 + (size_t)eb * H_ + hcg);

        for (int t = 0; t < T_; ++t) {
            // prefetch U for this step (h-independent)
            ushort4_t u[4];
#pragma unroll
            for (int q = 0; q < 4; ++q)
                u[q] = *(const ushort4_t*)(a.U[q] + ((size_t)t * B_ + eb) * H_ + hcg);
            // stage full h into LDS (wide cooperative load -> max MLP)
            const unsigned short* hp = t ? (a.Hall + (size_t)(t - 1) * B_ * H_) : a.h0c;
#pragma unroll
            for (int it = 0; it < 16; ++it) {
                int id = it * 256 + tid;
                int row = id >> 6, c8 = (id & 63) * 8;
                ushort8_t v = *(const ushort8_t*)(hp + row * H_ + c8);
                *(ushort8_t*)&hs[row * 520 + c8] = v;
            }
            __syncthreads();
            f32x4 acc[4] = {{0.f,0.f,0.f,0.f},{0.f,0.f,0.f,0.f},{0.f,0.f,0.f,0.f},{0.f,0.f,0.f,0.f}};
#pragma unroll
            for (int kc = 0; kc < 16; ++kc) {
#pragma unroll
                for (int nt = 0; nt < 4; ++nt) {
                    bf16x8 bfr = *(const bf16x8*)&hs[(nt * 16 + l16) * 520 + kc * 32 + quad * 8];
                    acc[nt] = mfma16(afrag[kc], bfr, acc[nt]);
                }
            }
#pragma unroll
            for (int nt = 0; nt < 4; ++nt)
#pragma unroll
                for (int r = 0; r < 4; ++r)
                    xch[g * 1040 + (quad * 4 + r) * 65 + nt * 16 + l16] = acc[nt][r];
            __syncthreads();
            ushort4_t hnew;
#pragma unroll
            for (int r = 0; r < 4; ++r) {
                float pi = xch[0 * 1040 + (ehc + r) * 65 + eb] + b2f(u[0][r]) + wb[0][r];
                float pf = xch[1 * 1040 + (ehc + r) * 65 + eb] + b2f(u[1][r]) + wb[1][r];
                float po = xch[2 * 1040 + (ehc + r) * 65 + eb] + b2f(u[2][r]) + wb[2][r];
                float pc = xch[3 * 1040 + (ehc + r) * 65 + eb] + b2f(u[3][r]) + wb[3][r];
                float it = 1.f / (1.f + __expf(-pi));
                float ft = 1.f / (1.f + __expf(-pf));
                float ot = 1.f / (1.f + __expf(-po));
                float ct = tanhf(pc);
                float cn = ft * c[r] + it * ct;
                c[r] = cn;
                hnew[r] = f2b(ot * cn);
            }
            {
                union { ushort4_t s4; unsigned long long q; } hu;
                hu.s4 = hnew;
                __hip_atomic_store((unsigned long long*)(a.Hall + ((size_t)t * B_ + eb) * H_ + hcg),
                                   hu.q, __ATOMIC_RELAXED, __HIP_MEMORY_SCOPE_AGENT);
            }
            asm volatile("s_waitcnt vmcnt(0)" ::: "memory");
            __syncthreads();   // all waves' h stores drained
            // single-LINE barrier: parallel per-WG flag stores to distinct words of one
            // 128B line (no serialization, far-writes merge at L3); poll = ONE line
            // fetch (bar[lane&31]). WG0 publishes the isolated AGGF epoch for proj.
            if (tid == 0)
                __hip_atomic_store(&a.bar[j], t + 1, __ATOMIC_RELAXED, __HIP_MEMORY_SCOPE_AGENT);
            if (t + 1 < T_ || j == 0) {
                if (g == 0) {
                    bool done;
                    do {
                        int v = __hip_atomic_load(&a.bar[lane & 31], __ATOMIC_RELAXED, __HIP_MEMORY_SCOPE_AGENT);
                        done = __all(v >= t + 1);
                        if (!done) __builtin_amdgcn_s_sleep(1);
                    } while (!done);
                    if (j == 0 && lane == 0)
                        __hip_atomic_store(&a.bar[AGGF_], t + 1, __ATOMIC_RELAXED, __HIP_MEMORY_SCOPE_AGENT);
                }
                if (t + 1 < T_) __syncthreads();
            }
        }
    } else {
        // -------- projection WG: t-group batched tiles (G=4 timesteps share one Ct
        // tile load). t-major strided job order; epoch-gated on the isolated AGGF line.
        unsigned short* As = (unsigned short*)pool;              // [4][64][72]
        unsigned short* Bs = (unsigned short*)(pool + 36864);    // [128][72]
        const int wv = tid >> 6;
        const int mw = (wv & 1) * 32, nw = (wv >> 1) * 64;
        const int NJ = NTG_ * NTN_;                              // 632 jobs
        int hiF = 0;   // high-water mark of observed epoch
        for (int q = (int)blockIdx.x - NR_; q < NJ; q += NPW_) {
            const int tg = q / NTN_, n0 = (q % NTN_) * 128;
            const int tb = tg * 4;
            const int need = (tb + 4 < T_) ? tb + 4 : T_;        // epoch required
            if (need > hiF) {
                if (tid < 64) {   // one wave polls the isolated AGGF line
                    while (__hip_atomic_load(&a.bar[AGGF_], __ATOMIC_RELAXED, __HIP_MEMORY_SCOPE_AGENT) < need)
                        __builtin_amdgcn_s_sleep(8);
                }
                __syncthreads();
                hiF = need;
            }
            f32x4 acc[4][2][4] = {};    // [tt][mt][nt], all indexing compile-time
            for (int k0 = 0; k0 < H_; k0 += 64) {
                // stage As: 4 t-slices of 64x64 (clamped to t=29 for tail group)
#pragma unroll
                for (int tt = 0; tt < 4; ++tt) {
                    int tA = tb + tt; if (tA >= T_) tA = T_ - 1;
                    const unsigned short* Ap = a.Hall + (size_t)tA * B_ * H_;
                    int id = tid;
#pragma unroll
                    for (int it = 0; it < 2; ++it, id += 256) {
                        int row = id >> 3, c8 = (id & 7) * 8;
                        *(ushort8_t*)&As[tt * 4608 + row * 72 + c8] =
                            *(const ushort8_t*)(Ap + (size_t)row * H_ + k0 + c8);
                    }
                }
                // stage Bs: 128x64
                {
                    int id2 = tid;
#pragma unroll
                    for (int it = 0; it < 4; ++it, id2 += 256) {
                        int row = id2 >> 3, c8 = (id2 & 7) * 8;
                        int gn = n0 + row;
                        ushort8_t v = {0, 0, 0, 0, 0, 0, 0, 0};
                        if (gn < V_) v = *(const ushort8_t*)(a.Ct + (size_t)gn * H_ + k0 + c8);
                        *(ushort8_t*)&Bs[row * 72 + c8] = v;
                    }
                }
                __syncthreads();
#pragma unroll
                for (int kk = 0; kk < 2; ++kk) {
                    bf16x8 bf[4];
#pragma unroll
                    for (int nt = 0; nt < 4; ++nt)
                        bf[nt] = *(const bf16x8*)&Bs[(nw + nt * 16 + l16) * 72 + kk * 32 + quad * 8];
#pragma unroll
                    for (int tt = 0; tt < 4; ++tt) {
                        bf16x8 af[2];
#pragma unroll
                        for (int mt = 0; mt < 2; ++mt)
                            af[mt] = *(const bf16x8*)&As[tt * 4608 + (mw + mt * 16 + l16) * 72 + kk * 32 + quad * 8];
#pragma unroll
                        for (int mt = 0; mt < 2; ++mt)
#pragma unroll
                            for (int nt = 0; nt < 4; ++nt)
                                acc[tt][mt][nt] = mfma16(af[mt], bf[nt], acc[tt][mt][nt]);
                    }
                }
                __syncthreads();
            }
#pragma unroll
            for (int tt = 0; tt < 4; ++tt) {
                const int t = tb + tt;
                if (t >= T_) continue;
#pragma unroll
                for (int mt = 0; mt < 2; ++mt)
#pragma unroll
                    for (int nt = 0; nt < 4; ++nt) {
                        int col = n0 + nw + nt * 16 + l16;
                        if (col >= V_) continue;
                        float bv = a.Cb[col];
                        int bb = mw + mt * 16 + quad * 4;
#pragma unroll
                        for (int r = 0; r < 4; ++r) {
                            int orow = (bb + r) * T_ + t;
                            a.out[(size_t)orow * V_ + col] = acc[tt][mt][nt][r] + bv;
                        }
                    }
            }
        }
    }
}

extern "C" void kernel_launch(void* const* d_in, const int* in_sizes, int n_in,
                              void* d_out, int out_size, void* d_ws, size_t ws_size,
                              hipStream_t stream) {
    (void)in_sizes; (void)n_in; (void)out_size; (void)ws_size;
    const int* captions = (const int*)d_in[0];
    const float* features = (const float*)d_in[1];
    const float* h0 = (const float*)d_in[2];
    const float* c0 = (const float*)d_in[3];
    const float* Bemb = (const float*)d_in[4];
    const float *iVW[4], *iVb[4], *iSW[4], *iSb[4], *iUW[4], *iUb[4], *iWW[4], *iWb[4];
    for (int g = 0; g < 4; ++g) {
        const int base = 5 + 8 * g;
        iVW[g] = (const float*)d_in[base + 0];
        iVb[g] = (const float*)d_in[base + 1];
        iSW[g] = (const float*)d_in[base + 2];
        iSb[g] = (const float*)d_in[base + 3];
        iUW[g] = (const float*)d_in[base + 4];
        iUb[g] = (const float*)d_in[base + 5];
        iWW[g] = (const float*)d_in[base + 6];
        iWb[g] = (const float*)d_in[base + 7];
    }
    const float* CW = (const float*)d_in[37];
    const float* Cb = (const float*)d_in[38];

    char* w = (char*)d_ws;
    auto alloc = [&](size_t bytes) -> void* {
        void* p = (void*)w;
        w += (bytes + 255) & ~(size_t)255;
        return p;
    };
    int* dbar = (int*)alloc(8192);   // flag line (words 0..31) + isolated AGGF line
    unsigned short* cH0 = (unsigned short*)alloc((size_t)B_ * H_ * 2);
    unsigned short *wVt[4], *wSt[4], *wUt[4], *wWt[4];
    for (int g = 0; g < 4; ++g) wVt[g] = (unsigned short*)alloc((size_t)FD_ * 320 * 2);
    for (int g = 0; g < 4; ++g) wSt[g] = (unsigned short*)alloc((size_t)FD_ * FD_ * 2);
    for (int g = 0; g < 4; ++g) wUt[g] = (unsigned short*)alloc((size_t)H_ * FD_ * 2);
    for (int g = 0; g < 4; ++g) wWt[g] = (unsigned short*)alloc((size_t)H_ * H_ * 2);
    unsigned short* wCt = (unsigned short*)alloc((size_t)V_ * H_ * 2);
    unsigned short* wX = (unsigned short*)alloc((size_t)B_ * T_ * 304 * 2);
    unsigned short* bufA[4];
    for (int g = 0; g < 4; ++g) bufA[g] = (unsigned short*)alloc((size_t)B_ * T_ * FD_ * 2);
    unsigned short* Hall = (unsigned short*)alloc((size_t)B_ * T_ * H_ * 2);

    // ---- dispatch 1: prep (transposes + build_x + h0 + flags)
    {
        PrepA p{};
        for (int g = 0; g < 4; ++g) {
            p.tsrc[g * 3 + 0] = iSW[g]; p.tdst[g * 3 + 0] = wSt[g];
            p.tsrc[g * 3 + 1] = iUW[g]; p.tdst[g * 3 + 1] = wUt[g];
            p.tsrc[g * 3 + 2] = iWW[g]; p.tdst[g * 3 + 2] = wWt[g];
            p.tsrc[12 + g] = iVW[g];    p.tdst[12 + g] = wVt[g];
        }
        p.tsrc[16] = CW; p.tdst[16] = wCt;
        p.captions = captions; p.features = features; p.Bemb = Bemb; p.X = wX;
        p.h0 = h0; p.cH0 = cH0; p.bar = dbar;
        prep_k<<<dim3(11128), 256, 0, stream>>>(p);
    }

    // ---- dispatch 2: fused 3-stage chain (240 WGs, 2/CU)
    {
        ChainA ca{};
        ca.X = wX;
        for (int g = 0; g < 4; ++g) {
            ca.Vt[g] = wVt[g]; ca.Vb[g] = iVb[g];
            ca.St[g] = wSt[g]; ca.Sb[g] = iSb[g];
            ca.Ut[g] = wUt[g]; ca.Ub[g] = iUb[g];
            ca.U[g] = bufA[g];
        }
        chain_k<<<dim3(240), 256, 0, stream>>>(ca);
    }

    // ---- dispatch 3: mega (recurrence + overlapped projection)
    {
        MegaA ma{};
        ma.h0c = cH0;
        for (int g = 0; g < 4; ++g) {
            ma.Wt[g] = wWt[g]; ma.Wb[g] = iWb[g]; ma.U[g] = bufA[g];
        }
        ma.c0 = c0;
        ma.Hall = Hall;
        ma.bar = dbar;
        ma.Ct = wCt;
        ma.Cb = Cb;
        ma.out = (float*)d_out;
        mega_k<<<dim3(NR_ + NPW_), 256, 0, stream>>>(ma);
    }
}